// Round 1
// baseline (269.930 us; speedup 1.0000x reference)
//
#include <hip/hip_runtime.h>
#include <math.h>

#define NN   20000
#define NE   320000
#define FIN  128
#define FHID 256
#define FOUT 64

// ---------- CSR build ----------
__global__ void k_init(float* deg, int* cnt) {
    int i = blockIdx.x * blockDim.x + threadIdx.x;
    if (i < NN) { deg[i] = 1.0f; cnt[i] = 0; }   // self-loop weight 1.0 pre-added
}

__global__ void k_deg(const int* __restrict__ dst, const float* __restrict__ ew,
                      float* deg, int* cnt) {
    int e = blockIdx.x * blockDim.x + threadIdx.x;
    if (e < NE) {
        int d = dst[e];
        atomicAdd(&deg[d], ew[e]);
        atomicAdd(&cnt[d], 1);
    }
}

__global__ void k_dinv(const float* __restrict__ deg, float* __restrict__ dinv) {
    int i = blockIdx.x * blockDim.x + threadIdx.x;
    if (i < NN) {
        float dg = deg[i];
        dinv[i] = dg > 0.0f ? 1.0f / sqrtf(dg) : 0.0f;
    }
}

// single-block inclusive scan (Hillis-Steele over 1024-chunks); also zeros cnt
__global__ __launch_bounds__(1024) void k_scan(int* cnt, int* off) {
    __shared__ int sm[1024];
    __shared__ int s_carry;
    int tid = threadIdx.x;
    if (tid == 0) { s_carry = 0; off[0] = 0; }
    __syncthreads();
    for (int base = 0; base < NN; base += 1024) {
        int i = base + tid;
        int v = (i < NN) ? cnt[i] : 0;
        sm[tid] = v;
        __syncthreads();
        for (int d = 1; d < 1024; d <<= 1) {
            int t = (tid >= d) ? sm[tid - d] : 0;
            __syncthreads();
            sm[tid] += t;
            __syncthreads();
        }
        int inc = sm[tid] + s_carry;
        __syncthreads();
        if (tid == 1023) s_carry = inc;
        if (i < NN) { off[i + 1] = inc; cnt[i] = 0; }
        __syncthreads();
    }
}

__global__ void k_scatter(const int* __restrict__ dst, const int* __restrict__ off,
                          int* cnt, int* eid) {
    int e = blockIdx.x * blockDim.x + threadIdx.x;
    if (e < NE) {
        int d = dst[e];
        int p = off[d] + atomicAdd(&cnt[d], 1);
        eid[p] = e;
    }
}

// ---------- layer 1: A = S @ X  (128 cols), one block (128 thr) per node ----------
__global__ __launch_bounds__(128) void k_aggx(
    const float* __restrict__ x, const int* __restrict__ src,
    const float* __restrict__ ew, const float* __restrict__ dinv,
    const int* __restrict__ off, const int* __restrict__ eid,
    float* __restrict__ A) {
    int n = blockIdx.x;
    int tid = threadIdx.x;
    float acc = 0.0f;
    int p0 = off[n], p1 = off[n + 1];
    for (int p = p0; p < p1; ++p) {
        int e = eid[p];
        int s = src[e];
        float coef = ew[e] * dinv[s];
        acc += coef * x[(size_t)s * FIN + tid];
    }
    float dn = dinv[n];
    acc = dn * (acc + dn * x[(size_t)n * FIN + tid]);
    A[(size_t)n * FIN + tid] = acc;
}

// ---------- C1 = relu(A @ W1 + b1): 8 rows/block, 256 thr = 256 cols ----------
__global__ __launch_bounds__(256) void k_gemm1(
    const float* __restrict__ A, const float* __restrict__ W1,
    const float* __restrict__ b1, float* __restrict__ C1) {
    __shared__ float As[8][FIN];
    int tid = threadIdx.x;
    int row0 = blockIdx.x * 8;
    for (int i = tid; i < 8 * FIN; i += 256)
        As[i >> 7][i & 127] = A[(size_t)(row0 + (i >> 7)) * FIN + (i & 127)];
    __syncthreads();
    float acc[8] = {};
    for (int k = 0; k < FIN; ++k) {
        float wv = W1[(size_t)k * FHID + tid];
        #pragma unroll
        for (int r = 0; r < 8; ++r) acc[r] += As[r][k] * wv;
    }
    float bias = b1[tid];
    #pragma unroll
    for (int r = 0; r < 8; ++r)
        C1[(size_t)(row0 + r) * FHID + tid] = fmaxf(acc[r] + bias, 0.0f);
}

// ---------- G = C1 @ W2: 16 rows/block, thread = (col 0..63, rowgroup 0..3) ----------
__global__ __launch_bounds__(256) void k_gemm2(
    const float* __restrict__ C1, const float* __restrict__ W2,
    float* __restrict__ G) {
    __shared__ float Cs[16][FHID];
    int tid = threadIdx.x;
    int row0 = blockIdx.x * 16;
    for (int i = tid; i < 16 * FHID; i += 256)
        Cs[i >> 8][i & 255] = C1[(size_t)(row0 + (i >> 8)) * FHID + (i & 255)];
    __syncthreads();
    int c = tid & 63, rr = tid >> 6;
    float acc[4] = {};
    for (int k = 0; k < FHID; ++k) {
        float wv = W2[(size_t)k * FOUT + c];
        #pragma unroll
        for (int j = 0; j < 4; ++j) acc[j] += Cs[rr * 4 + j][k] * wv;
    }
    #pragma unroll
    for (int j = 0; j < 4; ++j)
        G[(size_t)(row0 + rr * 4 + j) * FOUT + c] = acc[j];
}

// ---------- out = softmax(S @ G + b2): one wave per node, lane = class ----------
__global__ __launch_bounds__(256) void k_agg2sm(
    const float* __restrict__ G, const int* __restrict__ src,
    const float* __restrict__ ew, const float* __restrict__ dinv,
    const int* __restrict__ off, const int* __restrict__ eid,
    const float* __restrict__ b2, float* __restrict__ out) {
    int wid = threadIdx.x >> 6;
    int c = threadIdx.x & 63;
    int n = blockIdx.x * 4 + wid;
    float acc = 0.0f;
    int p0 = off[n], p1 = off[n + 1];
    for (int p = p0; p < p1; ++p) {
        int e = eid[p];
        int s = src[e];
        acc += ew[e] * dinv[s] * G[(size_t)s * FOUT + c];
    }
    float dn = dinv[n];
    float logit = dn * (acc + dn * G[(size_t)n * FOUT + c]) + b2[c];
    float m = logit;
    #pragma unroll
    for (int d = 32; d; d >>= 1) m = fmaxf(m, __shfl_xor(m, d, 64));
    float ev = expf(logit - m);
    float ssum = ev;
    #pragma unroll
    for (int d = 32; d; d >>= 1) ssum += __shfl_xor(ssum, d, 64);
    out[(size_t)n * FOUT + c] = ev / ssum;
}

extern "C" void kernel_launch(void* const* d_in, const int* in_sizes, int n_in,
                              void* d_out, int out_size, void* d_ws, size_t ws_size,
                              hipStream_t stream) {
    const float* x  = (const float*)d_in[0];
    const int*   ei = (const int*)d_in[1];     // [2, NE] int
    const float* ew = (const float*)d_in[2];
    // d_in[3..6] = W_gat, att_src, att_dst, b_gat — DEAD in the reference.
    const float* W1 = (const float*)d_in[7];
    const float* b1 = (const float*)d_in[8];
    const float* W2 = (const float*)d_in[9];
    const float* b2 = (const float*)d_in[10];

    const int* srcv = ei;
    const int* dstv = ei + NE;

    char* ws = (char*)d_ws;
    size_t o = 0;
    auto alloc = [&](size_t bytes) {
        void* p = ws + o;
        o = (o + bytes + 255) & ~(size_t)255;
        return p;
    };
    float* deg  = (float*)alloc(NN * sizeof(float));
    float* dinv = (float*)alloc(NN * sizeof(float));
    int*   cnt  = (int*)alloc(NN * sizeof(int));
    int*   off  = (int*)alloc((NN + 1) * sizeof(int));
    int*   eid  = (int*)alloc(NE * sizeof(int));
    float* A    = (float*)alloc((size_t)NN * FIN * sizeof(float));
    float* C1   = (float*)alloc((size_t)NN * FHID * sizeof(float));
    float* G    = A;  // A is dead after k_gemm1; reuse for G (5.12MB <= 10.24MB)

    k_init   <<<(NN + 255) / 256, 256, 0, stream>>>(deg, cnt);
    k_deg    <<<(NE + 255) / 256, 256, 0, stream>>>(dstv, ew, deg, cnt);
    k_dinv   <<<(NN + 255) / 256, 256, 0, stream>>>(deg, dinv);
    k_scan   <<<1, 1024, 0, stream>>>(cnt, off);
    k_scatter<<<(NE + 255) / 256, 256, 0, stream>>>(dstv, off, cnt, eid);
    k_aggx   <<<NN, 128, 0, stream>>>(x, srcv, ew, dinv, off, eid, A);
    k_gemm1  <<<NN / 8, 256, 0, stream>>>(A, W1, b1, C1);
    k_gemm2  <<<NN / 16, 256, 0, stream>>>(C1, W2, G);
    k_agg2sm <<<NN / 4, 256, 0, stream>>>(G, srcv, ew, dinv, off, eid, b2, (float*)d_out);
}

// Round 2
// 175.334 us; speedup vs baseline: 1.5395x; 1.5395x over previous
//
#include <hip/hip_runtime.h>
#include <math.h>

#define NN   20000
#define NE   320000
#define FIN  128
#define FHID 256
#define FOUT 64

// ---------- CSR build ----------
__global__ void k_init(float* deg, int* cnt) {
    int i = blockIdx.x * blockDim.x + threadIdx.x;
    if (i < NN) { deg[i] = 1.0f; cnt[i] = 0; }   // self-loop weight 1.0 pre-added
}

__global__ void k_deg(const int* __restrict__ dst, const float* __restrict__ ew,
                      float* __restrict__ deg, int* __restrict__ cnt) {
    int e = blockIdx.x * blockDim.x + threadIdx.x;
    if (e < NE) {
        int d = dst[e];
        atomicAdd(&deg[d], ew[e]);
        atomicAdd(&cnt[d], 1);
    }
}

__global__ void k_dinv(const float* __restrict__ deg, float* __restrict__ dinv) {
    int i = blockIdx.x * blockDim.x + threadIdx.x;
    if (i < NN) {
        float dg = deg[i];
        dinv[i] = dg > 0.0f ? rsqrtf(dg) : 0.0f;
    }
}

// single-block scan via wave-shuffles: 3 barriers/chunk instead of ~20
__global__ __launch_bounds__(1024) void k_scan(int* cnt, int* off) {
    __shared__ int wsum[16];
    __shared__ int s_carry;
    int tid = threadIdx.x;
    int lane = tid & 63, w = tid >> 6;
    if (tid == 0) { s_carry = 0; off[0] = 0; }
    __syncthreads();
    for (int base = 0; base < NN; base += 1024) {
        int i = base + tid;
        int v = (i < NN) ? cnt[i] : 0;
        int sc = v;
        #pragma unroll
        for (int d = 1; d < 64; d <<= 1) {
            int t = __shfl_up(sc, d, 64);
            if (lane >= d) sc += t;
        }
        if (lane == 63) wsum[w] = sc;
        __syncthreads();                       // (also fences prev-chunk s_carry write)
        if (w == 0) {
            int ws = (lane < 16) ? wsum[lane] : 0;
            #pragma unroll
            for (int d = 1; d < 16; d <<= 1) {
                int t = __shfl_up(ws, d, 64);
                if (lane >= d) ws += t;
            }
            if (lane < 16) wsum[lane] = ws;    // inclusive wave sums
        }
        __syncthreads();
        int wprefix = (w == 0) ? 0 : wsum[w - 1];
        int inc = sc + wprefix + s_carry;
        __syncthreads();                       // all reads of s_carry done
        if (tid == 1023) s_carry = inc;
        if (i < NN) { off[i + 1] = inc; cnt[i] = 0; }
        __syncthreads();
    }
}

// scatter with fully-precomputed coefficient: coef = ew * dinv[s] * dinv[d]
__global__ void k_scatter(const int* __restrict__ src, const int* __restrict__ dst,
                          const float* __restrict__ ew, const float* __restrict__ dinv,
                          const int* __restrict__ off, int* __restrict__ cnt,
                          int2* __restrict__ ep) {
    int e = blockIdx.x * blockDim.x + threadIdx.x;
    if (e < NE) {
        int d = dst[e], s = src[e];
        float c = ew[e] * dinv[s] * dinv[d];
        int p = off[d] + atomicAdd(&cnt[d], 1);
        ep[p] = make_int2(s, __float_as_int(c));
    }
}

// ---------- layer-1 aggregate: A = S @ X. wave per node, float2/lane, unroll 4 ----------
__global__ __launch_bounds__(256) void k_aggx(
    const float* __restrict__ x, const int2* __restrict__ ep,
    const float* __restrict__ dinv, const int* __restrict__ off,
    float* __restrict__ A) {
    int lane = threadIdx.x & 63;
    int n = (blockIdx.x << 2) + (threadIdx.x >> 6);
    const float* xc = x + (lane << 1);
    float ax = 0.0f, ay = 0.0f;
    int p = off[n], p1 = off[n + 1];
    for (; p + 4 <= p1; p += 4) {
        int2 e0 = ep[p], e1 = ep[p + 1], e2 = ep[p + 2], e3 = ep[p + 3];
        float2 v0 = *(const float2*)(xc + ((size_t)e0.x << 7));
        float2 v1 = *(const float2*)(xc + ((size_t)e1.x << 7));
        float2 v2 = *(const float2*)(xc + ((size_t)e2.x << 7));
        float2 v3 = *(const float2*)(xc + ((size_t)e3.x << 7));
        float c0 = __int_as_float(e0.y), c1 = __int_as_float(e1.y);
        float c2 = __int_as_float(e2.y), c3 = __int_as_float(e3.y);
        ax += c0 * v0.x + c1 * v1.x + c2 * v2.x + c3 * v3.x;
        ay += c0 * v0.y + c1 * v1.y + c2 * v2.y + c3 * v3.y;
    }
    for (; p < p1; ++p) {
        int2 e = ep[p];
        float2 v = *(const float2*)(xc + ((size_t)e.x << 7));
        float c = __int_as_float(e.y);
        ax += c * v.x;
        ay += c * v.y;
    }
    float dn = dinv[n];
    float s2 = dn * dn;
    float2 xv = *(const float2*)(xc + ((size_t)n << 7));
    ax += s2 * xv.x;
    ay += s2 * xv.y;
    *(float2*)(A + ((size_t)n << 7) + (lane << 1)) = make_float2(ax, ay);
}

// ---------- fused MLP: G = relu(A@W1+b1)@W2, 32 rows/block, G written over A (stride 128) ----------
#define FMA8(J, AV, W0, W1V)                                              \
    acc[J][0] += (AV) * (W0).x; acc[J][1] += (AV) * (W0).y;               \
    acc[J][2] += (AV) * (W0).z; acc[J][3] += (AV) * (W0).w;               \
    acc[J][4] += (AV) * (W1V).x; acc[J][5] += (AV) * (W1V).y;             \
    acc[J][6] += (AV) * (W1V).z; acc[J][7] += (AV) * (W1V).w;

__global__ __launch_bounds__(256) void k_mlp(
    const float* __restrict__ W1, const float* __restrict__ b1,
    const float* __restrict__ W2, float* __restrict__ AG) {
    __shared__ float lds[32 * FHID];           // 32KB; phase1 uses first 16KB as A-tile
    int tid = threadIdx.x;
    int row0 = blockIdx.x * 32;

    // stage A tile (32 x 128) coalesced
    {
        const float4* Af = (const float4*)(AG + (size_t)row0 * FIN);
        float4* Lf = (float4*)lds;
        #pragma unroll
        for (int i = 0; i < 4; ++i) Lf[tid + i * 256] = Af[tid + i * 256];
    }
    __syncthreads();

    int cg = tid & 31, rg = tid >> 5;          // 32 colgrps x 8 cols; 8 rowgrps x 4 rows
    int c0 = cg * 8, r0 = rg * 4;

    float acc[4][8] = {};
    for (int k = 0; k < FIN; k += 4) {
        float4 a0 = *(const float4*)&lds[(r0 + 0) * FIN + k];
        float4 a1 = *(const float4*)&lds[(r0 + 1) * FIN + k];
        float4 a2 = *(const float4*)&lds[(r0 + 2) * FIN + k];
        float4 a3 = *(const float4*)&lds[(r0 + 3) * FIN + k];
        #pragma unroll
        for (int kk = 0; kk < 4; ++kk) {
            float4 w0 = *(const float4*)&W1[(size_t)(k + kk) * FHID + c0];
            float4 w1 = *(const float4*)&W1[(size_t)(k + kk) * FHID + c0 + 4];
            float av0 = kk == 0 ? a0.x : kk == 1 ? a0.y : kk == 2 ? a0.z : a0.w;
            float av1 = kk == 0 ? a1.x : kk == 1 ? a1.y : kk == 2 ? a1.z : a1.w;
            float av2 = kk == 0 ? a2.x : kk == 1 ? a2.y : kk == 2 ? a2.z : a2.w;
            float av3 = kk == 0 ? a3.x : kk == 1 ? a3.y : kk == 2 ? a3.z : a3.w;
            FMA8(0, av0, w0, w1)
            FMA8(1, av1, w0, w1)
            FMA8(2, av2, w0, w1)
            FMA8(3, av3, w0, w1)
        }
    }
    float4 bA = *(const float4*)&b1[c0];
    float4 bB = *(const float4*)&b1[c0 + 4];
    __syncthreads();                           // done reading A-tile
    #pragma unroll
    for (int j = 0; j < 4; ++j) {
        float4 o0 = make_float4(fmaxf(acc[j][0] + bA.x, 0.f), fmaxf(acc[j][1] + bA.y, 0.f),
                                fmaxf(acc[j][2] + bA.z, 0.f), fmaxf(acc[j][3] + bA.w, 0.f));
        float4 o1 = make_float4(fmaxf(acc[j][4] + bB.x, 0.f), fmaxf(acc[j][5] + bB.y, 0.f),
                                fmaxf(acc[j][6] + bB.z, 0.f), fmaxf(acc[j][7] + bB.w, 0.f));
        *(float4*)&lds[(r0 + j) * FHID + c0] = o0;
        *(float4*)&lds[(r0 + j) * FHID + c0 + 4] = o1;
    }
    __syncthreads();

    // phase 2: G(32x64) = Cs(32x256) @ W2(256x64); c = 2 cols/lane
    int c = (tid & 31) * 2;
    float acc2[4][2] = {};
    for (int k = 0; k < FHID; k += 4) {
        float4 v0 = *(const float4*)&lds[(r0 + 0) * FHID + k];
        float4 v1 = *(const float4*)&lds[(r0 + 1) * FHID + k];
        float4 v2 = *(const float4*)&lds[(r0 + 2) * FHID + k];
        float4 v3 = *(const float4*)&lds[(r0 + 3) * FHID + k];
        #pragma unroll
        for (int kk = 0; kk < 4; ++kk) {
            float2 wv = *(const float2*)&W2[(size_t)(k + kk) * FOUT + c];
            float av0 = kk == 0 ? v0.x : kk == 1 ? v0.y : kk == 2 ? v0.z : v0.w;
            float av1 = kk == 0 ? v1.x : kk == 1 ? v1.y : kk == 2 ? v1.z : v1.w;
            float av2 = kk == 0 ? v2.x : kk == 1 ? v2.y : kk == 2 ? v2.z : v2.w;
            float av3 = kk == 0 ? v3.x : kk == 1 ? v3.y : kk == 2 ? v3.z : v3.w;
            acc2[0][0] += av0 * wv.x; acc2[0][1] += av0 * wv.y;
            acc2[1][0] += av1 * wv.x; acc2[1][1] += av1 * wv.y;
            acc2[2][0] += av2 * wv.x; acc2[2][1] += av2 * wv.y;
            acc2[3][0] += av3 * wv.x; acc2[3][1] += av3 * wv.y;
        }
    }
    // write G in-place over A rows (stride 128, first 64 cols) — safe: this block
    // already staged its own A rows and no other block touches them.
    #pragma unroll
    for (int j = 0; j < 4; ++j)
        *(float2*)(AG + ((size_t)(row0 + r0 + j) << 7) + c) = make_float2(acc2[j][0], acc2[j][1]);
}

// ---------- layer-2 aggregate + bias + softmax: wave per node, lane = class ----------
__global__ __launch_bounds__(256) void k_agg2sm(
    const float* __restrict__ G, const int2* __restrict__ ep,
    const float* __restrict__ dinv, const int* __restrict__ off,
    const float* __restrict__ b2, float* __restrict__ out) {
    int lane = threadIdx.x & 63;
    int n = (blockIdx.x << 2) + (threadIdx.x >> 6);
    const float* gc = G + lane;
    float acc = 0.0f;
    int p = off[n], p1 = off[n + 1];
    for (; p + 4 <= p1; p += 4) {
        int2 e0 = ep[p], e1 = ep[p + 1], e2 = ep[p + 2], e3 = ep[p + 3];
        float v0 = gc[(size_t)e0.x << 7];
        float v1 = gc[(size_t)e1.x << 7];
        float v2 = gc[(size_t)e2.x << 7];
        float v3 = gc[(size_t)e3.x << 7];
        acc += __int_as_float(e0.y) * v0 + __int_as_float(e1.y) * v1
             + __int_as_float(e2.y) * v2 + __int_as_float(e3.y) * v3;
    }
    for (; p < p1; ++p) {
        int2 e = ep[p];
        acc += __int_as_float(e.y) * gc[(size_t)e.x << 7];
    }
    float dn = dinv[n];
    float logit = acc + dn * dn * gc[(size_t)n << 7] + b2[lane];
    float m = logit;
    #pragma unroll
    for (int d = 32; d; d >>= 1) m = fmaxf(m, __shfl_xor(m, d, 64));
    float ev = expf(logit - m);
    float ssum = ev;
    #pragma unroll
    for (int d = 32; d; d >>= 1) ssum += __shfl_xor(ssum, d, 64);
    out[((size_t)n << 6) + lane] = ev / ssum;
}

extern "C" void kernel_launch(void* const* d_in, const int* in_sizes, int n_in,
                              void* d_out, int out_size, void* d_ws, size_t ws_size,
                              hipStream_t stream) {
    const float* x  = (const float*)d_in[0];
    const int*   ei = (const int*)d_in[1];     // [2, NE]
    const float* ew = (const float*)d_in[2];
    // d_in[3..6] = W_gat, att_src, att_dst, b_gat — DEAD in the reference.
    const float* W1 = (const float*)d_in[7];
    const float* b1 = (const float*)d_in[8];
    const float* W2 = (const float*)d_in[9];
    const float* b2 = (const float*)d_in[10];

    const int* srcv = ei;
    const int* dstv = ei + NE;

    char* ws = (char*)d_ws;
    size_t o = 0;
    auto alloc = [&](size_t bytes) {
        void* p = ws + o;
        o = (o + bytes + 255) & ~(size_t)255;
        return p;
    };
    float* deg  = (float*)alloc(NN * sizeof(float));
    float* dinv = (float*)alloc(NN * sizeof(float));
    int*   cnt  = (int*)alloc(NN * sizeof(int));
    int*   off  = (int*)alloc((NN + 1) * sizeof(int));
    int2*  ep   = (int2*)alloc((size_t)NE * sizeof(int2));
    float* AG   = (float*)alloc((size_t)NN * FIN * sizeof(float));  // A, then G in-place

    k_init   <<<(NN + 255) / 256, 256, 0, stream>>>(deg, cnt);
    k_deg    <<<(NE + 255) / 256, 256, 0, stream>>>(dstv, ew, deg, cnt);
    k_dinv   <<<(NN + 255) / 256, 256, 0, stream>>>(deg, dinv);
    k_scan   <<<1, 1024, 0, stream>>>(cnt, off);
    k_scatter<<<(NE + 255) / 256, 256, 0, stream>>>(srcv, dstv, ew, dinv, off, cnt, ep);
    k_aggx   <<<NN / 4, 256, 0, stream>>>(x, ep, dinv, off, AG);
    k_mlp    <<<NN / 32, 256, 0, stream>>>(W1, b1, W2, AG);
    k_agg2sm <<<NN / 4, 256, 0, stream>>>(AG, ep, dinv, off, b2, (float*)d_out);
}